// Round 1
// 400.618 us; speedup vs baseline: 1.0336x; 1.0336x over previous
//
#include <hip/hip_runtime.h>
#include <hip/hip_bf16.h>
#include <cstdint>
#include <cstddef>

#define HIDDEN 1024
#define BATCH 16
#define SEQ 2048
#define M_TOTAL (BATCH*SEQ)
#define NEG_INF -1000000000.0f

typedef unsigned short u16;
typedef __bf16 bf16x8 __attribute__((ext_vector_type(8)));
typedef unsigned short u16x8 __attribute__((ext_vector_type(8)));
typedef unsigned short u16x4 __attribute__((ext_vector_type(4)));
typedef float f32x4 __attribute__((ext_vector_type(4)));

typedef const __attribute__((address_space(1))) void* gas_ptr;
typedef __attribute__((address_space(3))) void* las_ptr;

__device__ __forceinline__ u16 f2bf(float f) {
    unsigned int x = __float_as_uint(f);
    unsigned int r = (x + 0x7fffu + ((x >> 16) & 1u)) >> 16;
    return (u16)r;
}

__device__ __forceinline__ float fast_tanh(float x) {
    float e = __expf(2.0f * x);
    return 1.0f - 2.0f / (e + 1.0f);
}

// ---------------------------------------------------------------------------
// q_proj[b,n] = sum_k query[b,k] * W1[k,n]   (fp32)
// 512 threads: 8-way K-split (was 4-way/256thr -> 1 blk/CU latency-exposed)
// ---------------------------------------------------------------------------
__global__ __launch_bounds__(512) void qproj_kernel(
    const float* __restrict__ q, const float* __restrict__ W1,
    float* __restrict__ qp)
{
    const int b  = blockIdx.y;
    const int tl = threadIdx.x & 63;
    const int kc = threadIdx.x >> 6;        // 0..7
    const int n  = blockIdx.x * 64 + tl;
    __shared__ float red[8][64];

    const float* qrow = q + b * HIDDEN;
    float acc = 0.f;
    #pragma unroll 8
    for (int k = kc * 128; k < kc * 128 + 128; ++k)
        acc += qrow[k] * W1[(size_t)k * HIDDEN + n];
    red[kc][tl] = acc;
    __syncthreads();
    if (kc == 0) {
        float s = 0.f;
        #pragma unroll
        for (int i = 0; i < 8; ++i) s += red[i][tl];
        qp[b * HIDDEN + n] = s;
    }
}

// ---------------------------------------------------------------------------
// W2T[n][k] = bf16(W2[k][n])
// ---------------------------------------------------------------------------
__global__ __launch_bounds__(256) void w2t_kernel(
    const float* __restrict__ W2, u16* __restrict__ W2T)
{
    __shared__ float tile[64][65];
    const int n0 = blockIdx.x * 64, k0 = blockIdx.y * 64;
    const int tid = threadIdx.x;
    const int c = tid & 63, rb = tid >> 6;
    #pragma unroll
    for (int i = 0; i < 16; ++i) {
        int r = rb + i * 4;
        tile[r][c] = W2[(size_t)(k0 + r) * HIDDEN + n0 + c];
    }
    __syncthreads();
    #pragma unroll
    for (int i = 0; i < 16; ++i) {
        int r = rb + i * 4;
        W2T[(size_t)(n0 + r) * HIDDEN + k0 + c] = f2bf(tile[c][r]);
    }
}

// ---------------------------------------------------------------------------
// keys (fp32, row-major) -> keys_bf (bf16, row-major).
// M_TOTAL*HIDDEN/4 = 8388608 float4 -> 4096 blocks x 256 thr x 8 float4
// (was 32768 one-float4 blocks; grid-stride removes dispatch overhead).
// ---------------------------------------------------------------------------
__global__ __launch_bounds__(256) void conv_kernel(
    const float* __restrict__ in, u16* __restrict__ out)
{
    int i0 = blockIdx.x * 256 + threadIdx.x;    // 1048576 threads
    #pragma unroll
    for (int r = 0; r < 8; ++r) {
        int i = i0 + r * (4096 * 256);
        float4 f = ((const float4*)in)[i];
        u16x4 p;
        p[0] = f2bf(f.x); p[1] = f2bf(f.y); p[2] = f2bf(f.z); p[3] = f2bf(f.w);
        ((u16x4*)out)[i] = p;
    }
}

// ---------------------------------------------------------------------------
// scores v2: bf16 A (pre-converted) and B via global_load_lds(16B) with
// XOR-swizzled LDS ([row][chunk^(row&7)], chunk = 16B unit). 128x128 tile,
// BK=64, mfma 16x16x32. grid (8 nt, 256 mt).
//
// XCD swizzle (R1): default mapping gives XCD = lid%8 = nt -> every XCD
// streams ALL 64MB of keysb through its private 4MB L2 (512MB L2-fill,
// FETCH_SIZE 266MB vs ~70MB ideal). Remap so each XCD owns a 32-m-tile
// band and the 8 blocks sharing an A-tile are consecutive on ONE XCD:
//   lid = bx + 8*by; xcd = lid&7; j = lid>>3; nt = j&7; mt = xcd*32 + j>>3
// Bijective (2048 % 8 == 0). A-tile (256KB) + W2T (2MB) stay L2-resident.
//
// Epilogue: part[slot][m] = sum_{64-col slice} tanh(acc+qp)*v
// ---------------------------------------------------------------------------
#define BM 128
#define BN 128
#define BK 64

__global__ __launch_bounds__(256) void scores_v2_kernel(
    const u16*   __restrict__ keysb,
    const u16*   __restrict__ W2T,
    const float* __restrict__ qp,
    const float* __restrict__ v,
    float*       __restrict__ part)
{
    __shared__ __align__(16) u16 Alds[BM * BK];
    __shared__ __align__(16) u16 Blds[BN * BK];

    const int tid  = threadIdx.x;
    const int lid  = blockIdx.x + (blockIdx.y << 3);
    const int xcd  = lid & 7;
    const int j    = lid >> 3;
    const int nt   = j & 7;
    const int mt   = (xcd << 5) + (j >> 3);
    const int n0   = nt * BN;
    const int m0   = mt * BM;
    const int wave = tid >> 6, lane = tid & 63;
    const int wr = wave >> 1, wc = wave & 1;
    const int quad = lane >> 4, c16 = lane & 15;

    // per-thread staging coords: idx = i*256 + tid; r = idx>>3, c = idx&7
    const int sr = tid >> 3;                // row 0..31 (+32 per i)
    const int sc = tid & 7;                 // chunk 0..7

    f32x4 acc[4][4];
    #pragma unroll
    for (int i = 0; i < 4; ++i)
        #pragma unroll
        for (int jj = 0; jj < 4; ++jj)
            acc[i][jj] = f32x4{0.f, 0.f, 0.f, 0.f};

    for (int kt = 0; kt < HIDDEN; kt += BK) {
        __syncthreads();
        // A: 128 rows x 8 chunks of 16B; 4 issues/thread
        #pragma unroll
        for (int i = 0; i < 4; ++i) {
            int r = sr + i * 32;
            int csw = sc ^ (r & 7);
            const u16* src = keysb + (size_t)(m0 + r) * HIDDEN + kt + csw * 8;
            las_ptr dst = (las_ptr)((char*)Alds + (i * 256 + wave * 64) * 16);
            __builtin_amdgcn_global_load_lds((gas_ptr)src, dst, 16, 0, 0);
        }
        // B: same for W2T rows n0..n0+127
        #pragma unroll
        for (int i = 0; i < 4; ++i) {
            int r = sr + i * 32;
            int csw = sc ^ (r & 7);
            const u16* src = W2T + (size_t)(n0 + r) * HIDDEN + kt + csw * 8;
            las_ptr dst = (las_ptr)((char*)Blds + (i * 256 + wave * 64) * 16);
            __builtin_amdgcn_global_load_lds((gas_ptr)src, dst, 16, 0, 0);
        }
        __syncthreads();

        #pragma unroll
        for (int ks = 0; ks < BK; ks += 32) {
            const int ch = (ks >> 3) + quad;          // 16B chunk in row
            bf16x8 af[4], bfr[4];
            #pragma unroll
            for (int i = 0; i < 4; ++i) {
                int row = wr * 64 + i * 16 + c16;
                af[i] = __builtin_bit_cast(bf16x8,
                    *(const u16x8*)&Alds[row * BK + ((ch ^ (row & 7)) << 3)]);
            }
            #pragma unroll
            for (int jj = 0; jj < 4; ++jj) {
                int row = wc * 64 + jj * 16 + c16;
                bfr[jj] = __builtin_bit_cast(bf16x8,
                    *(const u16x8*)&Blds[row * BK + ((ch ^ (row & 7)) << 3)]);
            }
            #pragma unroll
            for (int i = 0; i < 4; ++i)
                #pragma unroll
                for (int jj = 0; jj < 4; ++jj)
                    acc[i][jj] = __builtin_amdgcn_mfma_f32_16x16x32_bf16(
                        af[i], bfr[jj], acc[i][jj], 0, 0, 0);
        }
    }

    const int b = m0 >> 11;
    float qv[4], vv[4];
    #pragma unroll
    for (int jj = 0; jj < 4; ++jj) {
        int n = n0 + wc * 64 + jj * 16 + c16;
        qv[jj] = qp[b * HIDDEN + n];
        vv[jj] = v[n];
    }
    const int slot = nt * 2 + wc;
    #pragma unroll
    for (int i = 0; i < 4; ++i) {
        #pragma unroll
        for (int r = 0; r < 4; ++r) {
            float s = 0.f;
            #pragma unroll
            for (int jj = 0; jj < 4; ++jj)
                s += fast_tanh(acc[i][jj][r] + qv[jj]) * vv[jj];
            s += __shfl_xor(s, 1);
            s += __shfl_xor(s, 2);
            s += __shfl_xor(s, 4);
            s += __shfl_xor(s, 8);
            if (c16 == 0) {
                int m = m0 + wr * 64 + i * 16 + quad * 4 + r;
                part[(size_t)slot * M_TOTAL + m] = s;
            }
        }
    }
}

// ---------------------------------------------------------------------------
// scores v1 (fallback if ws too small): inline fp32->bf16 convert staging
// ---------------------------------------------------------------------------
#define LDA 72

__global__ __launch_bounds__(256) void scores_v1_kernel(
    const float* __restrict__ keys,
    const u16*   __restrict__ W2T,
    const float* __restrict__ qp,
    const float* __restrict__ v,
    float*       __restrict__ part)
{
    __shared__ __align__(16) u16 Alds[BM][LDA];
    __shared__ __align__(16) u16 Blds[BN][LDA];

    const int tid  = threadIdx.x;
    const int nt   = blockIdx.x;
    const int n0   = nt * BN;
    const int m0   = blockIdx.y * BM;
    const int wave = tid >> 6, lane = tid & 63;
    const int wr = wave >> 1, wc = wave & 1;
    const int quad = lane >> 4, c16 = lane & 15;

    f32x4 acc[4][4];
    #pragma unroll
    for (int i = 0; i < 4; ++i)
        #pragma unroll
        for (int jj = 0; jj < 4; ++jj)
            acc[i][jj] = f32x4{0.f, 0.f, 0.f, 0.f};

    for (int kt = 0; kt < HIDDEN; kt += BK) {
        __syncthreads();
        const float* gA = keys + (size_t)m0 * HIDDEN + kt;
        #pragma unroll
        for (int i = 0; i < 8; ++i) {
            int idx = tid + i * 256;
            int r = idx >> 4, c4 = idx & 15;
            float4 f = *(const float4*)(gA + (size_t)r * HIDDEN + c4 * 4);
            u16x4 pk;
            pk[0] = f2bf(f.x); pk[1] = f2bf(f.y);
            pk[2] = f2bf(f.z); pk[3] = f2bf(f.w);
            *(u16x4*)&Alds[r][c4 * 4] = pk;
        }
        #pragma unroll
        for (int i = 0; i < 4; ++i) {
            int idx = tid + i * 256;
            int r = idx >> 3, c8 = idx & 7;
            uint4 raw = ((const uint4*)(W2T + (size_t)(n0 + r) * HIDDEN + kt))[c8];
            *(uint4*)&Blds[r][c8 * 8] = raw;
        }
        __syncthreads();

        #pragma unroll
        for (int ks = 0; ks < BK; ks += 32) {
            bf16x8 af[4], bfr[4];
            #pragma unroll
            for (int i = 0; i < 4; ++i)
                af[i] = __builtin_bit_cast(bf16x8,
                    *(const u16x8*)&Alds[wr * 64 + i * 16 + c16][ks + quad * 8]);
            #pragma unroll
            for (int jj = 0; jj < 4; ++jj)
                bfr[jj] = __builtin_bit_cast(bf16x8,
                    *(const u16x8*)&Blds[wc * 64 + jj * 16 + c16][ks + quad * 8]);
            #pragma unroll
            for (int i = 0; i < 4; ++i)
                #pragma unroll
                for (int jj = 0; jj < 4; ++jj)
                    acc[i][jj] = __builtin_amdgcn_mfma_f32_16x16x32_bf16(
                        af[i], bfr[jj], acc[i][jj], 0, 0, 0);
        }
    }

    const int b = m0 >> 11;
    float qv[4], vv[4];
    #pragma unroll
    for (int jj = 0; jj < 4; ++jj) {
        int n = n0 + wc * 64 + jj * 16 + c16;
        qv[jj] = qp[b * HIDDEN + n];
        vv[jj] = v[n];
    }
    const int slot = nt * 2 + wc;
    #pragma unroll
    for (int i = 0; i < 4; ++i) {
        #pragma unroll
        for (int r = 0; r < 4; ++r) {
            float s = 0.f;
            #pragma unroll
            for (int jj = 0; jj < 4; ++jj)
                s += fast_tanh(acc[i][jj][r] + qv[jj]) * vv[jj];
            s += __shfl_xor(s, 1);
            s += __shfl_xor(s, 2);
            s += __shfl_xor(s, 4);
            s += __shfl_xor(s, 8);
            if (c16 == 0) {
                int m = m0 + wr * 64 + i * 16 + quad * 4 + r;
                part[(size_t)slot * M_TOTAL + m] = s;
            }
        }
    }
}

// ---------------------------------------------------------------------------
// softmax: sum 16 part slots -> mask -> softmax. 1024 thr, 2 s each.
// ---------------------------------------------------------------------------
__global__ __launch_bounds__(1024) void softmax_kernel(
    const float* __restrict__ part, const int* __restrict__ mask,
    float* __restrict__ attn)
{
    const int b = blockIdx.x, tid = threadIdx.x;
    const int wave = tid >> 6, lane = tid & 63;
    __shared__ float red[16];
    float sc[2];
    float mx = -1e30f;
    #pragma unroll
    for (int j = 0; j < 2; ++j) {
        int s = tid + j * 1024;
        float a = 0.f;
        #pragma unroll
        for (int p = 0; p < 16; ++p)
            a += part[(size_t)p * M_TOTAL + b * SEQ + s];
        if (mask[b * SEQ + s] == 0) a = NEG_INF;
        sc[j] = a;
        mx = fmaxf(mx, a);
    }
    #pragma unroll
    for (int o = 32; o > 0; o >>= 1) mx = fmaxf(mx, __shfl_xor(mx, o));
    if (lane == 0) red[wave] = mx;
    __syncthreads();
    #pragma unroll
    for (int w = 0; w < 16; ++w) mx = fmaxf(mx, red[w]);
    float sum = 0.f;
    #pragma unroll
    for (int j = 0; j < 2; ++j) { sc[j] = __expf(sc[j] - mx); sum += sc[j]; }
    #pragma unroll
    for (int o = 32; o > 0; o >>= 1) sum += __shfl_xor(sum, o);
    __syncthreads();
    if (lane == 0) red[wave] = sum;
    __syncthreads();
    sum = 0.f;
    #pragma unroll
    for (int w = 0; w < 16; ++w) sum += red[w];
    float inv = 1.0f / sum;
    #pragma unroll
    for (int j = 0; j < 2; ++j)
        attn[b * SEQ + tid + j * 1024] = sc[j] * inv;
}

// ---------------------------------------------------------------------------
// context stage 1: ctxp[b*64+sch][h] = sum_{s in 32-chunk} attn*values
// grid (16 b, 64 sch) = 1024 blocks (4/CU)
// NOTE: the wv!=0 branch is block-uniform (w[s] broadcast) and ~half of
// attn weights are exactly 0 (mask) -> legitimately skips ~64MB of reads.
// ---------------------------------------------------------------------------
__global__ __launch_bounds__(256) void ctx_part_kernel(
    const float* __restrict__ values, const float* __restrict__ attn,
    float* __restrict__ ctxp)
{
    const int b = blockIdx.x, sch = blockIdx.y, tid = threadIdx.x;
    __shared__ float w[32];
    if (tid < 32) w[tid] = attn[b * SEQ + sch * 32 + tid];
    __syncthreads();
    float4 acc = {0.f, 0.f, 0.f, 0.f};
    const float4* V = (const float4*)(values
        + (size_t)b * SEQ * HIDDEN + (size_t)sch * 32 * HIDDEN);
    #pragma unroll 4
    for (int s = 0; s < 32; ++s) {
        float wv = w[s];
        if (wv != 0.0f) {
            float4 x = V[(size_t)s * (HIDDEN / 4) + tid];
            acc.x += wv * x.x; acc.y += wv * x.y;
            acc.z += wv * x.z; acc.w += wv * x.w;
        }
    }
    ((float4*)(ctxp + (size_t)(b * 64 + sch) * HIDDEN))[tid] = acc;
}

// context stage 2: ctx[b][h] = sum_sch ctxp[b*64+sch][h]
__global__ __launch_bounds__(256) void ctx_reduce_kernel(
    const float* __restrict__ ctxp, float* __restrict__ ctx)
{
    const int b = blockIdx.x, tid = threadIdx.x;
    float4 acc = {0.f, 0.f, 0.f, 0.f};
    const float4* P = (const float4*)(ctxp + (size_t)b * 64 * HIDDEN);
    #pragma unroll 8
    for (int s = 0; s < 64; ++s) {
        float4 x = P[(size_t)s * (HIDDEN / 4) + tid];
        acc.x += x.x; acc.y += x.y; acc.z += x.z; acc.w += x.w;
    }
    ((float4*)(ctx + (size_t)b * HIDDEN))[tid] = acc;
}

// ---------------------------------------------------------------------------
extern "C" void kernel_launch(void* const* d_in, const int* in_sizes, int n_in,
                              void* d_out, int out_size, void* d_ws, size_t ws_size,
                              hipStream_t stream)
{
    const float* query  = (const float*)d_in[0];
    const float* keys   = (const float*)d_in[1];
    const float* values = (const float*)d_in[2];
    const int*   mask   = (const int*)d_in[3];
    const float* W1     = (const float*)d_in[4];
    const float* W2     = (const float*)d_in[5];
    const float* v      = (const float*)d_in[6];
    float* out = (float*)d_out;

    // ws layout:
    //   qp      64 KiB
    //   W2T      2 MiB  (bf16 [n][k])
    //   part     2 MiB  (16 x 32768 f32)
    //   ctxp     4 MiB  (1024 x 1024 f32)     [big path]
    //   keys_bf 64 MiB  (bf16 [32768][1024])  [big path]
    char* ws = (char*)d_ws;
    float* qp     = (float*)ws;
    u16*   w2t    = (u16*)(ws + (64 << 10));
    float* part   = (float*)(ws + (64 << 10) + (2 << 20));
    float* ctxp   = (float*)(ws + (64 << 10) + (4 << 20));
    u16*   keysb  = (u16*)(ws + (64 << 10) + (8 << 20));
    const size_t WS_BIG = (64 << 10) + (8 << 20) + ((size_t)64 << 20);

    float* attn_out = out + BATCH * HIDDEN;

    qproj_kernel<<<dim3(16, 16), 512, 0, stream>>>(query, W1, qp);
    w2t_kernel  <<<dim3(16, 16), 256, 0, stream>>>(W2, w2t);

    if (ws_size >= WS_BIG) {
        // 8388608 float4 total = 4096 blocks x 256 thr x 8 (exact coverage)
        conv_kernel<<<4096, 256, 0, stream>>>(keys, keysb);
        scores_v2_kernel<<<dim3(8, 256), 256, 0, stream>>>(
            keysb, w2t, qp, v, part);
        softmax_kernel<<<16, 1024, 0, stream>>>(part, mask, attn_out);
        ctx_part_kernel<<<dim3(16, 64), 256, 0, stream>>>(
            values, attn_out, ctxp);
        ctx_reduce_kernel<<<16, 256, 0, stream>>>(ctxp, out);
    } else {
        scores_v1_kernel<<<dim3(8, 256), 256, 0, stream>>>(
            keys, w2t, qp, v, part);
        softmax_kernel<<<16, 1024, 0, stream>>>(part, mask, attn_out);
        if (ws_size >= (64 << 10) + (8 << 20)) {
            ctx_part_kernel<<<dim3(16, 64), 256, 0, stream>>>(
                values, attn_out, ctxp);
            ctx_reduce_kernel<<<16, 256, 0, stream>>>(ctxp, out);
        } else {
            hipMemsetAsync(d_out, 0, BATCH * HIDDEN * sizeof(float), stream);
            ctx_part_kernel<<<dim3(16, 64), 256, 0, stream>>>(
                values, attn_out, (float*)d_ws);
            ctx_reduce_kernel<<<16, 256, 0, stream>>>((float*)d_ws, out);
        }
    }
}

// Round 2
// 376.578 us; speedup vs baseline: 1.0996x; 1.0638x over previous
//
#include <hip/hip_runtime.h>
#include <hip/hip_bf16.h>
#include <cstdint>
#include <cstddef>

#define HIDDEN 1024
#define BATCH 16
#define SEQ 2048
#define M_TOTAL (BATCH*SEQ)
#define NEG_INF -1000000000.0f

typedef unsigned short u16;
typedef __bf16 bf16x8 __attribute__((ext_vector_type(8)));
typedef unsigned short u16x8 __attribute__((ext_vector_type(8)));
typedef unsigned short u16x4 __attribute__((ext_vector_type(4)));
typedef float f32x4 __attribute__((ext_vector_type(4)));

typedef const __attribute__((address_space(1))) void* gas_ptr;
typedef __attribute__((address_space(3))) void* las_ptr;

__device__ __forceinline__ u16 f2bf(float f) {
    unsigned int x = __float_as_uint(f);
    unsigned int r = (x + 0x7fffu + ((x >> 16) & 1u)) >> 16;
    return (u16)r;
}

__device__ __forceinline__ float fast_tanh(float x) {
    float e = __expf(2.0f * x);
    return 1.0f - 2.0f / (e + 1.0f);
}

// ---------------------------------------------------------------------------
// q_proj[b,n] = sum_k query[b,k] * W1[k,n]   (fp32)
// ---------------------------------------------------------------------------
__global__ __launch_bounds__(512) void qproj_kernel(
    const float* __restrict__ q, const float* __restrict__ W1,
    float* __restrict__ qp)
{
    const int b  = blockIdx.y;
    const int tl = threadIdx.x & 63;
    const int kc = threadIdx.x >> 6;        // 0..7
    const int n  = blockIdx.x * 64 + tl;
    __shared__ float red[8][64];

    const float* qrow = q + b * HIDDEN;
    float acc = 0.f;
    #pragma unroll 8
    for (int k = kc * 128; k < kc * 128 + 128; ++k)
        acc += qrow[k] * W1[(size_t)k * HIDDEN + n];
    red[kc][tl] = acc;
    __syncthreads();
    if (kc == 0) {
        float s = 0.f;
        #pragma unroll
        for (int i = 0; i < 8; ++i) s += red[i][tl];
        qp[b * HIDDEN + n] = s;
    }
}

// ---------------------------------------------------------------------------
// W2T[n][k] = bf16(W2[k][n])
// ---------------------------------------------------------------------------
__global__ __launch_bounds__(256) void w2t_kernel(
    const float* __restrict__ W2, u16* __restrict__ W2T)
{
    __shared__ float tile[64][65];
    const int n0 = blockIdx.x * 64, k0 = blockIdx.y * 64;
    const int tid = threadIdx.x;
    const int c = tid & 63, rb = tid >> 6;
    #pragma unroll
    for (int i = 0; i < 16; ++i) {
        int r = rb + i * 4;
        tile[r][c] = W2[(size_t)(k0 + r) * HIDDEN + n0 + c];
    }
    __syncthreads();
    #pragma unroll
    for (int i = 0; i < 16; ++i) {
        int r = rb + i * 4;
        W2T[(size_t)(n0 + r) * HIDDEN + k0 + c] = f2bf(tile[c][r]);
    }
}

// ---------------------------------------------------------------------------
// keys (fp32) -> keys_bf (bf16). Reverted to 32768 x 1-float4/thread (the
// R1 8-stream grid-stride variant looked ~10us slower end-to-end).
// ---------------------------------------------------------------------------
__global__ __launch_bounds__(256) void conv_kernel(
    const float* __restrict__ in, u16* __restrict__ out)
{
    int i = blockIdx.x * 256 + threadIdx.x;     // float4 index, 8M total
    float4 f = ((const float4*)in)[i];
    u16x4 p;
    p[0] = f2bf(f.x); p[1] = f2bf(f.y); p[2] = f2bf(f.z); p[3] = f2bf(f.w);
    ((u16x4*)out)[i] = p;
}

// ---------------------------------------------------------------------------
// scores v3: 256x256 tile, BK=64, 512 thr / 8 waves, 8-phase (4 phases per
// K-tile x 2-tile dbuf) schedule with counted vmcnt (T3+T4), setprio (T5),
// 16B-chunk XOR swizzle (proven 0-conflict), XCD-bijective block swizzle.
//
// Wave (wr=w>>2, wc=w&3) owns C rows {ms*128 + wr*64 + 0..63} x cols
// {ns*128 + wc*32 + 0..31} over ms,ns in {0,1} -> phase (ms,ns) reads only
// A-half ms and B-half ns. Phase order (0,0),(0,1),(1,0),(1,1); A-frags
// reused across the two ns phases.
//
// Staging: during tile T's 4 phases stage tile T+1's halves A0,B0,B1,A1
// into the opposite buffer (2 x global_load_lds = 2 vmcnt items each).
// vmcnt(4) before each phase barrier guarantees (traced window):
//   end T.ph4: lands t+1 A0,B0 (needed T+1.ph1)
//   end T.ph1: lands t   B1 from prior window... (steady-state: oldest 2
//   of 6-8 outstanding == the half needed 1 phase later). Last tile peeled
//   with vmcnt(2)/vmcnt(0). Prologue drains once (vmcnt(0)) - negligible.
// ---------------------------------------------------------------------------
#define NT3 16   // K tiles = HIDDEN/64

#define WAIT4 asm volatile("s_waitcnt vmcnt(4)" ::: "memory")
#define WAIT2 asm volatile("s_waitcnt vmcnt(2)" ::: "memory")
#define WAIT0 asm volatile("s_waitcnt vmcnt(0)" ::: "memory")
#define NOWAIT do {} while (0)

#define SBAR() do { __builtin_amdgcn_s_barrier(); \
                    asm volatile("" ::: "memory"); } while (0)

// stage one half-tile (128 rows x 64 k bf16 = 16KB) with pre-swizzled src
// (Rule 21: linear LDS dest + inverse-swizzled global source).
#define STAGE_HALF(SRC, ROW0, KT, LBASE)                                    \
    do {                                                                    \
        _Pragma("unroll")                                                   \
        for (int r_ = 0; r_ < 2; ++r_) {                                    \
            int idx_ = r_ * 512 + tid;                                      \
            int row_ = idx_ >> 3, c_ = idx_ & 7;                            \
            const u16* s_ = (SRC) + (size_t)((ROW0) + row_) * HIDDEN        \
                            + (KT) + ((c_ ^ (row_ & 7)) << 3);              \
            las_ptr d_ = (las_ptr)((char*)(LBASE)                           \
                            + (size_t)(r_ * 512 + (wave << 6)) * 16);       \
            __builtin_amdgcn_global_load_lds((gas_ptr)s_, d_, 16, 0, 0);    \
        }                                                                   \
    } while (0)

// LBASE: u16* buffer base; ROWL 0..255; CH 0..7 (16B chunk in 128B row)
#define LDFRAG(LBASE, ROWL, CH) __builtin_bit_cast(bf16x8,                  \
    *(const u16x8*)((LBASE) + (ROWL) * 64 + ((((CH) ^ ((ROWL) & 7))) << 3)))

#define PHASE(MS, NS, LOADA, STAGECODE, WAITCODE)                           \
    do {                                                                    \
        if (LOADA) {                                                        \
            _Pragma("unroll")                                               \
            for (int i_ = 0; i_ < 4; ++i_) {                                \
                int rowa_ = (MS) * 128 + wr * 64 + i_ * 16 + c16;           \
                af[i_][0] = LDFRAG(Acur, rowa_, quad);                      \
                af[i_][1] = LDFRAG(Acur, rowa_, 4 + quad);                  \
            }                                                               \
        }                                                                   \
        _Pragma("unroll")                                                   \
        for (int jj_ = 0; jj_ < 2; ++jj_) {                                 \
            int rowb_ = (NS) * 128 + wc * 32 + jj_ * 16 + c16;              \
            bfr[jj_][0] = LDFRAG(Bcur, rowb_, quad);                        \
            bfr[jj_][1] = LDFRAG(Bcur, rowb_, 4 + quad);                    \
        }                                                                   \
        STAGECODE;                                                          \
        WAITCODE;                                                           \
        SBAR();                                                             \
        __builtin_amdgcn_s_setprio(1);                                      \
        _Pragma("unroll")                                                   \
        for (int i_ = 0; i_ < 4; ++i_)                                      \
            _Pragma("unroll")                                               \
            for (int jj_ = 0; jj_ < 2; ++jj_) {                             \
                acc[MS][i_][NS][jj_] =                                      \
                    __builtin_amdgcn_mfma_f32_16x16x32_bf16(                \
                        af[i_][0], bfr[jj_][0], acc[MS][i_][NS][jj_],0,0,0);\
                acc[MS][i_][NS][jj_] =                                      \
                    __builtin_amdgcn_mfma_f32_16x16x32_bf16(                \
                        af[i_][1], bfr[jj_][1], acc[MS][i_][NS][jj_],0,0,0);\
            }                                                               \
        __builtin_amdgcn_s_setprio(0);                                      \
        SBAR();                                                             \
    } while (0)

__global__ __launch_bounds__(512) void scores_v3_kernel(
    const u16*   __restrict__ keysb,
    const u16*   __restrict__ W2T,
    const float* __restrict__ qp,
    const float* __restrict__ v,
    float*       __restrict__ part)
{
    // A: bytes [0, 65536)  = 2 bufs x 32KB (halves at +0/+16384)
    // B: bytes [65536, 131072)
    __shared__ __align__(16) u16 lds[65536];

    const int tid = threadIdx.x;
    // XCD-bijective swizzle: 512 wgs, 8 XCDs -> 64 each; each XCD owns a
    // 16-mtile band, nt cycles fastest within it (A-tile L2 reuse x4).
    const int lid = blockIdx.x + (blockIdx.y << 2);
    const int xcd = lid & 7;
    const int j8  = lid >> 3;
    const int nt  = j8 & 3;
    const int mt  = (xcd << 4) + (j8 >> 2);
    const int m0  = mt << 8;
    const int n0  = nt << 8;

    const int wave = tid >> 6, lane = tid & 63;
    const int wr = wave >> 2;       // 0..1
    const int wc = wave & 3;        // 0..3
    const int quad = lane >> 4, c16 = lane & 15;

    const u16* Akeys = keysb + (size_t)m0 * HIDDEN;
    const u16* Bw2t  = W2T   + (size_t)n0 * HIDDEN;

    f32x4 acc[2][4][2][2];
    #pragma unroll
    for (int a = 0; a < 2; ++a)
        #pragma unroll
        for (int i = 0; i < 4; ++i)
            #pragma unroll
            for (int c = 0; c < 2; ++c)
                #pragma unroll
                for (int d = 0; d < 2; ++d)
                    acc[a][i][c][d] = f32x4{0.f, 0.f, 0.f, 0.f};

    bf16x8 af[4][2], bfr[2][2];

    // prologue: tile 0 -> buf 0, drain once
    STAGE_HALF(Akeys, 0,   0, (char*)lds + 0);
    STAGE_HALF(Bw2t,  0,   0, (char*)lds + 65536);
    STAGE_HALF(Bw2t,  128, 0, (char*)lds + 65536 + 16384);
    STAGE_HALF(Akeys, 128, 0, (char*)lds + 16384);
    WAIT0;
    SBAR();

    for (int T = 0; T < NT3 - 1; ++T) {
        const int p = T & 1;
        const u16* Acur = (const u16*)((const char*)lds + p * 32768);
        const u16* Bcur = (const u16*)((const char*)lds + 65536 + p * 32768);
        char* Anext = (char*)lds + (p ^ 1) * 32768;
        char* Bnext = (char*)lds + 65536 + (p ^ 1) * 32768;
        const int ktn = (T + 1) * 64;

        PHASE(0, 0, true,  STAGE_HALF(Akeys, 0,   ktn, Anext),         WAIT4);
        PHASE(0, 1, false, STAGE_HALF(Bw2t,  0,   ktn, Bnext),         WAIT4);
        PHASE(1, 0, true,  STAGE_HALF(Bw2t,  128, ktn, Bnext + 16384), WAIT4);
        PHASE(1, 1, false, STAGE_HALF(Akeys, 128, ktn, Anext + 16384), WAIT4);
    }
    {   // last tile T=15, p=1, no staging; peeled waits cover B1/A1 landing
        const u16* Acur = (const u16*)((const char*)lds + 32768);
        const u16* Bcur = (const u16*)((const char*)lds + 65536 + 32768);
        PHASE(0, 0, true,  NOWAIT, WAIT2);
        PHASE(0, 1, false, NOWAIT, WAIT0);
        PHASE(1, 0, true,  NOWAIT, NOWAIT);
        PHASE(1, 1, false, NOWAIT, NOWAIT);
    }

    // epilogue: part[slot][m] = sum over wave's 64 cols of tanh(acc+qp)*v
    const int b = m0 >> 11;
    float qv[2][2], vv[2][2];
    #pragma unroll
    for (int ns = 0; ns < 2; ++ns)
        #pragma unroll
        for (int jj = 0; jj < 2; ++jj) {
            int n = n0 + ns * 128 + wc * 32 + jj * 16 + c16;
            qv[ns][jj] = qp[b * HIDDEN + n];
            vv[ns][jj] = v[n];
        }
    const int slot = (nt << 2) + wc;   // 16 slots
    #pragma unroll
    for (int ms = 0; ms < 2; ++ms)
        #pragma unroll
        for (int i = 0; i < 4; ++i)
            #pragma unroll
            for (int r = 0; r < 4; ++r) {
                float s = 0.f;
                #pragma unroll
                for (int ns = 0; ns < 2; ++ns)
                    #pragma unroll
                    for (int jj = 0; jj < 2; ++jj)
                        s += fast_tanh(acc[ms][i][ns][jj][r] + qv[ns][jj])
                             * vv[ns][jj];
                s += __shfl_xor(s, 1);
                s += __shfl_xor(s, 2);
                s += __shfl_xor(s, 4);
                s += __shfl_xor(s, 8);
                if (c16 == 0) {
                    int m = m0 + ms * 128 + wr * 64 + i * 16 + quad * 4 + r;
                    part[(size_t)slot * M_TOTAL + m] = s;
                }
            }
}

// ---------------------------------------------------------------------------
// scores v1 (fallback if ws too small): inline fp32->bf16 convert staging
// ---------------------------------------------------------------------------
#define BM 128
#define BN 128
#define BK 64
#define LDA 72

__global__ __launch_bounds__(256) void scores_v1_kernel(
    const float* __restrict__ keys,
    const u16*   __restrict__ W2T,
    const float* __restrict__ qp,
    const float* __restrict__ v,
    float*       __restrict__ part)
{
    __shared__ __align__(16) u16 Alds[BM][LDA];
    __shared__ __align__(16) u16 Blds[BN][LDA];

    const int tid  = threadIdx.x;
    const int nt   = blockIdx.x;
    const int n0   = nt * BN;
    const int m0   = blockIdx.y * BM;
    const int wave = tid >> 6, lane = tid & 63;
    const int wr = wave >> 1, wc = wave & 1;
    const int quad = lane >> 4, c16 = lane & 15;

    f32x4 acc[4][4];
    #pragma unroll
    for (int i = 0; i < 4; ++i)
        #pragma unroll
        for (int jj = 0; jj < 4; ++jj)
            acc[i][jj] = f32x4{0.f, 0.f, 0.f, 0.f};

    for (int kt = 0; kt < HIDDEN; kt += BK) {
        __syncthreads();
        const float* gA = keys + (size_t)m0 * HIDDEN + kt;
        #pragma unroll
        for (int i = 0; i < 8; ++i) {
            int idx = tid + i * 256;
            int r = idx >> 4, c4 = idx & 15;
            float4 f = *(const float4*)(gA + (size_t)r * HIDDEN + c4 * 4);
            u16x4 pk;
            pk[0] = f2bf(f.x); pk[1] = f2bf(f.y);
            pk[2] = f2bf(f.z); pk[3] = f2bf(f.w);
            *(u16x4*)&Alds[r][c4 * 4] = pk;
        }
        #pragma unroll
        for (int i = 0; i < 4; ++i) {
            int idx = tid + i * 256;
            int r = idx >> 3, c8 = idx & 7;
            uint4 raw = ((const uint4*)(W2T + (size_t)(n0 + r) * HIDDEN + kt))[c8];
            *(uint4*)&Blds[r][c8 * 8] = raw;
        }
        __syncthreads();

        #pragma unroll
        for (int ks = 0; ks < BK; ks += 32) {
            bf16x8 af[4], bfr[4];
            #pragma unroll
            for (int i = 0; i < 4; ++i)
                af[i] = __builtin_bit_cast(bf16x8,
                    *(const u16x8*)&Alds[wr * 64 + i * 16 + c16][ks + quad * 8]);
            #pragma unroll
            for (int jj = 0; jj < 4; ++jj)
                bfr[jj] = __builtin_bit_cast(bf16x8,
                    *(const u16x8*)&Blds[wc * 64 + jj * 16 + c16][ks + quad * 8]);
            #pragma unroll
            for (int i = 0; i < 4; ++i)
                #pragma unroll
                for (int jj = 0; jj < 4; ++jj)
                    acc[i][jj] = __builtin_amdgcn_mfma_f32_16x16x32_bf16(
                        af[i], bfr[jj], acc[i][jj], 0, 0, 0);
        }
    }

    const int b = m0 >> 11;
    float qv[4], vv[4];
    #pragma unroll
    for (int jj = 0; jj < 4; ++jj) {
        int n = n0 + wc * 64 + jj * 16 + c16;
        qv[jj] = qp[b * HIDDEN + n];
        vv[jj] = v[n];
    }
    const int slot = nt * 2 + wc;
    #pragma unroll
    for (int i = 0; i < 4; ++i) {
        #pragma unroll
        for (int r = 0; r < 4; ++r) {
            float s = 0.f;
            #pragma unroll
            for (int jj = 0; jj < 4; ++jj)
                s += fast_tanh(acc[i][jj][r] + qv[jj]) * vv[jj];
            s += __shfl_xor(s, 1);
            s += __shfl_xor(s, 2);
            s += __shfl_xor(s, 4);
            s += __shfl_xor(s, 8);
            if (c16 == 0) {
                int m = m0 + wr * 64 + i * 16 + quad * 4 + r;
                part[(size_t)slot * M_TOTAL + m] = s;
            }
        }
    }
}

// ---------------------------------------------------------------------------
// softmax: sum 16 part slots -> mask -> softmax. 1024 thr, 2 s each.
// ---------------------------------------------------------------------------
__global__ __launch_bounds__(1024) void softmax_kernel(
    const float* __restrict__ part, const int* __restrict__ mask,
    float* __restrict__ attn)
{
    const int b = blockIdx.x, tid = threadIdx.x;
    const int wave = tid >> 6, lane = tid & 63;
    __shared__ float red[16];
    float sc[2];
    float mx = -1e30f;
    #pragma unroll
    for (int j = 0; j < 2; ++j) {
        int s = tid + j * 1024;
        float a = 0.f;
        #pragma unroll
        for (int p = 0; p < 16; ++p)
            a += part[(size_t)p * M_TOTAL + b * SEQ + s];
        if (mask[b * SEQ + s] == 0) a = NEG_INF;
        sc[j] = a;
        mx = fmaxf(mx, a);
    }
    #pragma unroll
    for (int o = 32; o > 0; o >>= 1) mx = fmaxf(mx, __shfl_xor(mx, o));
    if (lane == 0) red[wave] = mx;
    __syncthreads();
    #pragma unroll
    for (int w = 0; w < 16; ++w) mx = fmaxf(mx, red[w]);
    float sum = 0.f;
    #pragma unroll
    for (int j = 0; j < 2; ++j) { sc[j] = __expf(sc[j] - mx); sum += sc[j]; }
    #pragma unroll
    for (int o = 32; o > 0; o >>= 1) sum += __shfl_xor(sum, o);
    __syncthreads();
    if (lane == 0) red[wave] = sum;
    __syncthreads();
    sum = 0.f;
    #pragma unroll
    for (int w = 0; w < 16; ++w) sum += red[w];
    float inv = 1.0f / sum;
    #pragma unroll
    for (int j = 0; j < 2; ++j)
        attn[b * SEQ + tid + j * 1024] = sc[j] * inv;
}

// ---------------------------------------------------------------------------
// context stage 1: ctxp[b*64+sch][h] = sum_{s in 32-chunk} attn*values
// ---------------------------------------------------------------------------
__global__ __launch_bounds__(256) void ctx_part_kernel(
    const float* __restrict__ values, const float* __restrict__ attn,
    float* __restrict__ ctxp)
{
    const int b = blockIdx.x, sch = blockIdx.y, tid = threadIdx.x;
    __shared__ float w[32];
    if (tid < 32) w[tid] = attn[b * SEQ + sch * 32 + tid];
    __syncthreads();
    float4 acc = {0.f, 0.f, 0.f, 0.f};
    const float4* V = (const float4*)(values
        + (size_t)b * SEQ * HIDDEN + (size_t)sch * 32 * HIDDEN);
    #pragma unroll 4
    for (int s = 0; s < 32; ++s) {
        float wv = w[s];
        if (wv != 0.0f) {
            float4 x = V[(size_t)s * (HIDDEN / 4) + tid];
            acc.x += wv * x.x; acc.y += wv * x.y;
            acc.z += wv * x.z; acc.w += wv * x.w;
        }
    }
    ((float4*)(ctxp + (size_t)(b * 64 + sch) * HIDDEN))[tid] = acc;
}

// context stage 2: ctx[b][h] = sum_sch ctxp[b*64+sch][h]
__global__ __launch_bounds__(256) void ctx_reduce_kernel(
    const float* __restrict__ ctxp, float* __restrict__ ctx)
{
    const int b = blockIdx.x, tid = threadIdx.x;
    float4 acc = {0.f, 0.f, 0.f, 0.f};
    const float4* P = (const float4*)(ctxp + (size_t)b * 64 * HIDDEN);
    #pragma unroll 8
    for (int s = 0; s < 64; ++s) {
        float4 x = P[(size_t)s * (HIDDEN / 4) + tid];
        acc.x += x.x; acc.y += x.y; acc.z += x.z; acc.w += x.w;
    }
    ((float4*)(ctx + (size_t)b * HIDDEN))[tid] = acc;
}

// ---------------------------------------------------------------------------
extern "C" void kernel_launch(void* const* d_in, const int* in_sizes, int n_in,
                              void* d_out, int out_size, void* d_ws, size_t ws_size,
                              hipStream_t stream)
{
    const float* query  = (const float*)d_in[0];
    const float* keys   = (const float*)d_in[1];
    const float* values = (const float*)d_in[2];
    const int*   mask   = (const int*)d_in[3];
    const float* W1     = (const float*)d_in[4];
    const float* W2     = (const float*)d_in[5];
    const float* v      = (const float*)d_in[6];
    float* out = (float*)d_out;

    // ws layout:
    //   qp      64 KiB
    //   W2T      2 MiB  (bf16 [n][k])
    //   part     2 MiB  (16 x 32768 f32)
    //   ctxp     4 MiB  (1024 x 1024 f32)     [big path]
    //   keys_bf 64 MiB  (bf16 [32768][1024])  [big path]
    char* ws = (char*)d_ws;
    float* qp     = (float*)ws;
    u16*   w2t    = (u16*)(ws + (64 << 10));
    float* part   = (float*)(ws + (64 << 10) + (2 << 20));
    float* ctxp   = (float*)(ws + (64 << 10) + (4 << 20));
    u16*   keysb  = (u16*)(ws + (64 << 10) + (8 << 20));
    const size_t WS_BIG = (64 << 10) + (8 << 20) + ((size_t)64 << 20);

    float* attn_out = out + BATCH * HIDDEN;

    qproj_kernel<<<dim3(16, 16), 512, 0, stream>>>(query, W1, qp);
    w2t_kernel  <<<dim3(16, 16), 256, 0, stream>>>(W2, w2t);

    if (ws_size >= WS_BIG) {
        conv_kernel<<<32768, 256, 0, stream>>>(keys, keysb);
        scores_v3_kernel<<<dim3(4, 128), 512, 0, stream>>>(
            keysb, w2t, qp, v, part);
        softmax_kernel<<<16, 1024, 0, stream>>>(part, mask, attn_out);
        ctx_part_kernel<<<dim3(16, 64), 256, 0, stream>>>(
            values, attn_out, ctxp);
        ctx_reduce_kernel<<<16, 256, 0, stream>>>(ctxp, out);
    } else {
        scores_v1_kernel<<<dim3(8, 256), 256, 0, stream>>>(
            keys, w2t, qp, v, part);
        softmax_kernel<<<16, 1024, 0, stream>>>(part, mask, attn_out);
        if (ws_size >= (64 << 10) + (8 << 20)) {
            ctx_part_kernel<<<dim3(16, 64), 256, 0, stream>>>(
                values, attn_out, ctxp);
            ctx_reduce_kernel<<<16, 256, 0, stream>>>(ctxp, out);
        } else {
            hipMemsetAsync(d_out, 0, BATCH * HIDDEN * sizeof(float), stream);
            ctx_part_kernel<<<dim3(16, 64), 256, 0, stream>>>(
                values, attn_out, (float*)d_ws);
            ctx_reduce_kernel<<<16, 256, 0, stream>>>((float*)d_ws, out);
        }
    }
}